// Round 1
// baseline (250.128 us; speedup 1.0000x reference)
//
#include <hip/hip_runtime.h>
#include <hip/hip_bf16.h>
#include <stdint.h>

#define NB   8
#define NN   2048
#define NE   16384
#define OBS  128
#define HID  256
#define OUTF 1024

__device__ __forceinline__ float4 f4fma(float w, float4 v, float4 a) {
    a.x = fmaf(w, v.x, a.x);
    a.y = fmaf(w, v.y, a.y);
    a.z = fmaf(w, v.z, a.z);
    a.w = fmaf(w, v.w, a.w);
    return a;
}

// counts[b][n] += 1 for each edge with dst==n  (self-loop handled as +1 later)
__global__ __launch_bounds__(256) void k_count(const int* __restrict__ edges,
                                               int* __restrict__ counts) {
    int idx = blockIdx.x * 256 + threadIdx.x;
    if (idx >= NB * NE) return;
    int b = idx / NE, e = idx - b * NE;
    int dst = edges[(size_t)b * 2 * NE + NE + e];
    atomicAdd(&counts[b * NN + dst], 1);
}

// Per-graph exclusive prefix sum over counts -> CSR offsets (+cursor copy),
// and dinv[n] = rsqrt(deg) with deg = counts + 1 (self-loop).
__global__ __launch_bounds__(256) void k_scan(const int* __restrict__ counts,
                                              int* __restrict__ offsets,
                                              int* __restrict__ cursor,
                                              float* __restrict__ dinv) {
    const int b = blockIdx.x, t = threadIdx.x;
    const int base = b * NN + t * 8;
    int local[8];
    int s = 0;
#pragma unroll
    for (int j = 0; j < 8; ++j) {
        int c = counts[base + j];
        local[j] = s;
        s += c;
        dinv[base + j] = rsqrtf((float)(c + 1));
    }
    __shared__ int sc[256];
    sc[t] = s;
    __syncthreads();
    for (int d = 1; d < 256; d <<= 1) {
        int v = (t >= d) ? sc[t - d] : 0;
        __syncthreads();
        if (t >= d) sc[t] += v;
        __syncthreads();
    }
    int excl = sc[t] - s;  // exclusive prefix of this thread's chunk
#pragma unroll
    for (int j = 0; j < 8; ++j) {
        int val = excl + local[j];
        offsets[b * (NN + 1) + t * 8 + j] = val;
        cursor[base + j] = val;
    }
    if (t == 0) offsets[b * (NN + 1) + NN] = NE;
}

// Scatter edges into CSR order (sorted by dst).
__global__ __launch_bounds__(256) void k_fill(const int* __restrict__ edges,
                                              int* __restrict__ cursor,
                                              int* __restrict__ csr) {
    int idx = blockIdx.x * 256 + threadIdx.x;
    if (idx >= NB * NE) return;
    int b = idx / NE, e = idx - b * NE;
    int src = edges[(size_t)b * 2 * NE + e];
    int dst = edges[(size_t)b * 2 * NE + NE + e];
    int pos = atomicAdd(&cursor[b * NN + dst], 1);
    csr[(size_t)b * NE + pos] = src;
}

// C[M][NO] = A[M][K] * W[K][NO]; M = NB*NN. Tiled 64x64, 256 threads, 4x4/thread.
template <int K, int NO>
__global__ __launch_bounds__(256) void gemm_f32(const float* __restrict__ A,
                                                const float* __restrict__ W,
                                                float* __restrict__ C) {
    __shared__ float As[16][68];  // [k][m], padded
    __shared__ float Ws[16][64];  // [k][n]
    const int tid = threadIdx.x;
    const int tx = tid & 15, ty = tid >> 4;
    const int row0 = blockIdx.x * 64, col0 = blockIdx.y * 64;
    float acc[4][4] = {};
    for (int kt = 0; kt < K; kt += 16) {
        {
            const int c = tid & 15, r = tid >> 4;
#pragma unroll
            for (int p = 0; p < 4; ++p)
                As[c][r + p * 16] = A[(size_t)(row0 + r + p * 16) * K + kt + c];
            const int wc = tid & 63, wr = tid >> 6;
#pragma unroll
            for (int p = 0; p < 4; ++p)
                Ws[wr + p * 4][wc] = W[(size_t)(kt + wr + p * 4) * NO + col0 + wc];
        }
        __syncthreads();
#pragma unroll
        for (int k = 0; k < 16; ++k) {
            const float4 a4 = *(const float4*)&As[k][ty * 4];
            const float4 b4 = *(const float4*)&Ws[k][tx * 4];
            const float av[4] = {a4.x, a4.y, a4.z, a4.w};
            const float bv[4] = {b4.x, b4.y, b4.z, b4.w};
#pragma unroll
            for (int i = 0; i < 4; ++i)
#pragma unroll
                for (int j = 0; j < 4; ++j)
                    acc[i][j] = fmaf(av[i], bv[j], acc[i][j]);
        }
        __syncthreads();
    }
#pragma unroll
    for (int i = 0; i < 4; ++i) {
        float4 o = make_float4(acc[i][0], acc[i][1], acc[i][2], acc[i][3]);
        *(float4*)&C[(size_t)(row0 + ty * 4 + i) * NO + col0 + tx * 4] = o;
    }
}

// Gather-aggregate one dst row per block: out = relu(bias + dinv_i^2*h[i] + sum norm*h[src]).
template <int F, int TPB>
__global__ __launch_bounds__(TPB) void k_agg(const float* __restrict__ h,
                                             const float* __restrict__ dinv,
                                             const int* __restrict__ csr,
                                             const int* __restrict__ offsets,
                                             const float* __restrict__ bias,
                                             float* __restrict__ out) {
    const int i = blockIdx.x, b = blockIdx.y, t = threadIdx.x;
    const float* hb = h + (size_t)b * NN * F;
    const float di = dinv[b * NN + i];
    const int o0 = offsets[b * (NN + 1) + i];
    const int o1 = offsets[b * (NN + 1) + i + 1];
    float4 acc = make_float4(0.f, 0.f, 0.f, 0.f);
    acc = f4fma(di * di, *(const float4*)&hb[(size_t)i * F + t * 4], acc);
    const int* cs = csr + (size_t)b * NE;
    const float* dv = dinv + b * NN;
    for (int e = o0; e < o1; ++e) {
        int s = cs[e];
        acc = f4fma(di * dv[s], *(const float4*)&hb[(size_t)s * F + t * 4], acc);
    }
    const float4 bi = *(const float4*)&bias[t * 4];
    float4 o;
    o.x = fmaxf(acc.x + bi.x, 0.f);
    o.y = fmaxf(acc.y + bi.y, 0.f);
    o.z = fmaxf(acc.z + bi.z, 0.f);
    o.w = fmaxf(acc.w + bi.w, 0.f);
    *(float4*)&out[((size_t)(b * NN) + i) * F + t * 4] = o;
}

extern "C" void kernel_launch(void* const* d_in, const int* in_sizes, int n_in,
                              void* d_out, int out_size, void* d_ws, size_t ws_size,
                              hipStream_t stream) {
    const float* nodes = (const float*)d_in[0];
    const int*   edges = (const int*)d_in[1];
    const float* W0    = (const float*)d_in[2];
    const float* b0    = (const float*)d_in[3];
    const float* W1    = (const float*)d_in[4];
    const float* b1    = (const float*)d_in[5];
    float* out = (float*)d_out;

    char* ws = (char*)d_ws;
    size_t off = 0;
    auto alloc = [&](size_t bytes) -> char* {
        char* p = ws + off;
        off = (off + bytes + 255) & ~(size_t)255;
        return p;
    };
    float* dinv   = (float*)alloc((size_t)NB * NN * 4);
    int*   counts = (int*)alloc((size_t)NB * NN * 4);
    int*   offs   = (int*)alloc((size_t)NB * (NN + 1) * 4);
    int*   cursor = (int*)alloc((size_t)NB * NN * 4);
    int*   csr    = (int*)alloc((size_t)NB * NE * 4);
    float* x1     = (float*)alloc((size_t)NB * NN * HID * 4);   // 16 MB
    float* hbuf   = (float*)alloc((size_t)NB * NN * OUTF * 4);  // 64 MB (h1 uses first 16 MB, then h2)

    hipMemsetAsync(counts, 0, (size_t)NB * NN * 4, stream);
    k_count<<<(NB * NE + 255) / 256, 256, 0, stream>>>(edges, counts);
    k_scan<<<NB, 256, 0, stream>>>(counts, offs, cursor, dinv);
    k_fill<<<(NB * NE + 255) / 256, 256, 0, stream>>>(edges, cursor, csr);

    // Layer 1: h1 = nodes @ W0 ; x1 = relu(agg(h1) + b0)
    gemm_f32<OBS, HID><<<dim3((NB * NN) / 64, HID / 64), 256, 0, stream>>>(nodes, W0, hbuf);
    k_agg<HID, 64><<<dim3(NN, NB), 64, 0, stream>>>(hbuf, dinv, csr, offs, b0, x1);

    // Layer 2: h2 = x1 @ W1 ; out = relu(agg(h2) + b1)
    gemm_f32<HID, OUTF><<<dim3((NB * NN) / 64, OUTF / 64), 256, 0, stream>>>(x1, W1, hbuf);
    k_agg<OUTF, 256><<<dim3(NN, NB), 256, 0, stream>>>(hbuf, dinv, csr, offs, b1, out);
}

// Round 2
// 84.901 us; speedup vs baseline: 2.9461x; 2.9461x over previous
//
#include <hip/hip_runtime.h>
#include <hip/hip_bf16.h>
#include <stdint.h>

#define NB   8
#define NN   2048
#define NE   16384
#define OBS  128
#define HID  256
#define OUTF 1024

using bfrag = __attribute__((ext_vector_type(8))) short;
using ffrag = __attribute__((ext_vector_type(4))) float;

__device__ __forceinline__ short f2bf(float f) {
    __hip_bfloat16 h = __float2bfloat16(f);
    return __builtin_bit_cast(short, h);
}
__device__ __forceinline__ float bf2f(short s) {
    return __uint_as_float(((unsigned)(unsigned short)s) << 16);
}
__device__ __forceinline__ unsigned packbf(float a, float b) {
    return ((unsigned)(unsigned short)f2bf(b) << 16) | (unsigned)(unsigned short)f2bf(a);
}

__device__ __forceinline__ void gload_lds16(const void* g, void* l) {
    __builtin_amdgcn_global_load_lds(
        (const __attribute__((address_space(1))) unsigned int*)g,
        (__attribute__((address_space(3))) unsigned int*)l, 16, 0, 0);
}

// ---------------- graph setup ----------------
__global__ __launch_bounds__(256) void k_count(const int* __restrict__ edges,
                                               int* __restrict__ counts) {
    int idx = blockIdx.x * 256 + threadIdx.x;
    if (idx >= NB * NE) return;
    int b = idx / NE, e = idx - b * NE;
    int dst = edges[(size_t)b * 2 * NE + NE + e];
    atomicAdd(&counts[b * NN + dst], 1);
}

__global__ __launch_bounds__(256) void k_scan(const int* __restrict__ counts,
                                              int* __restrict__ offsets,
                                              int* __restrict__ cursor,
                                              float* __restrict__ dinv) {
    const int b = blockIdx.x, t = threadIdx.x;
    const int base = b * NN + t * 8;
    int local[8];
    int s = 0;
#pragma unroll
    for (int j = 0; j < 8; ++j) {
        int c = counts[base + j];
        local[j] = s;
        s += c;
        dinv[base + j] = rsqrtf((float)(c + 1));
    }
    __shared__ int sc[256];
    sc[t] = s;
    __syncthreads();
    for (int d = 1; d < 256; d <<= 1) {
        int v = (t >= d) ? sc[t - d] : 0;
        __syncthreads();
        if (t >= d) sc[t] += v;
        __syncthreads();
    }
    int excl = sc[t] - s;
#pragma unroll
    for (int j = 0; j < 8; ++j) {
        int val = excl + local[j];
        offsets[b * (NN + 1) + t * 8 + j] = val;
        cursor[base + j] = val;
    }
    if (t == 0) offsets[b * (NN + 1) + NN] = NE;
}

__global__ __launch_bounds__(256) void k_fill(const int* __restrict__ edges,
                                              int* __restrict__ cursor,
                                              int* __restrict__ csr) {
    int idx = blockIdx.x * 256 + threadIdx.x;
    if (idx >= NB * NE) return;
    int b = idx / NE, e = idx - b * NE;
    int src = edges[(size_t)b * 2 * NE + e];
    int dst = edges[(size_t)b * 2 * NE + NE + e];
    int pos = atomicAdd(&cursor[b * NN + dst], 1);
    csr[(size_t)b * NE + pos] = src;
}

// W [K][N] f32 -> Wt [N][K] bf16
template <int K, int N>
__global__ __launch_bounds__(256) void k_wt(const float* __restrict__ W,
                                            short* __restrict__ Wt) {
    int idx = blockIdx.x * 256 + threadIdx.x;
    if (idx >= K * N) return;
    int n = idx / K, k = idx - n * K;
    Wt[idx] = f2bf(W[k * N + n]);
}

// ---------------- pre-GEMM aggregation (S x) ----------------
// z0 = S . nodes  (f32 in -> bf16 out, F=128). 64 thr x 2 elems.
__global__ __launch_bounds__(64) void k_agg0(const float* __restrict__ nodes,
                                             const float* __restrict__ dinv,
                                             const int* __restrict__ csr,
                                             const int* __restrict__ offs,
                                             unsigned* __restrict__ z0) {
    const int i = blockIdx.x, b = blockIdx.y, t = threadIdx.x;
    const float* xb = nodes + (size_t)b * NN * OBS;
    const float di = dinv[b * NN + i];
    const int o0 = offs[b * (NN + 1) + i], o1 = offs[b * (NN + 1) + i + 1];
    float2 v = *(const float2*)&xb[(size_t)i * OBS + t * 2];
    float ax = di * di * v.x, ay = di * di * v.y;
    const int* cs = csr + (size_t)b * NE;
    const float* dv = dinv + b * NN;
    for (int e = o0; e < o1; ++e) {
        int s = cs[e];
        float w = di * dv[s];
        float2 u = *(const float2*)&xb[(size_t)s * OBS + t * 2];
        ax = fmaf(w, u.x, ax);
        ay = fmaf(w, u.y, ay);
    }
    z0[(((size_t)b * NN + i) * OBS + t * 2) >> 1] = packbf(ax, ay);
}

// z1 = S . x1  (bf16 in -> bf16 out, F=256). 64 thr x 4 elems.
__global__ __launch_bounds__(64) void k_agg1(const short* __restrict__ x1,
                                             const float* __restrict__ dinv,
                                             const int* __restrict__ csr,
                                             const int* __restrict__ offs,
                                             unsigned* __restrict__ z1) {
    const int i = blockIdx.x, b = blockIdx.y, t = threadIdx.x;
    const short* xb = x1 + (size_t)b * NN * HID;
    const float di = dinv[b * NN + i];
    const int o0 = offs[b * (NN + 1) + i], o1 = offs[b * (NN + 1) + i + 1];
    uint2 raw = *(const uint2*)&xb[(size_t)i * HID + t * 4];
    float di2 = di * di;
    float a0 = di2 * __uint_as_float(raw.x << 16);
    float a1 = di2 * __uint_as_float(raw.x & 0xffff0000u);
    float a2 = di2 * __uint_as_float(raw.y << 16);
    float a3 = di2 * __uint_as_float(raw.y & 0xffff0000u);
    const int* cs = csr + (size_t)b * NE;
    const float* dv = dinv + b * NN;
    for (int e = o0; e < o1; ++e) {
        int s = cs[e];
        float w = di * dv[s];
        uint2 u = *(const uint2*)&xb[(size_t)s * HID + t * 4];
        a0 = fmaf(w, __uint_as_float(u.x << 16), a0);
        a1 = fmaf(w, __uint_as_float(u.x & 0xffff0000u), a1);
        a2 = fmaf(w, __uint_as_float(u.y << 16), a2);
        a3 = fmaf(w, __uint_as_float(u.y & 0xffff0000u), a3);
    }
    uint2 o;
    o.x = packbf(a0, a1);
    o.y = packbf(a2, a3);
    *(uint2*)&z1[(((size_t)b * NN + i) * HID + t * 4) >> 1] = o;
}

// ---------------- bf16 MFMA GEMM: C = relu(A @ Bt^T + bias) ----------------
// A [M][K] bf16 row-major, Bt [N][K] bf16 (pre-transposed weights).
// 128x128 tile, BK=64, 4 waves (2x2 of 64x64), double-buffered LDS,
// global_load_lds width-16 staging (m97 structure).
template <int K, int N, bool OUT_BF16>
__global__ __launch_bounds__(256, 2) void gemm_mfma(const short* __restrict__ A,
                                                    const short* __restrict__ Bt,
                                                    const float* __restrict__ bias,
                                                    void* __restrict__ Cv) {
    __shared__ short lds[2][2][128 * 64];  // [buf][A|B][row*64 + k] bf16
    const int tid = threadIdx.x;
    const int lane = tid & 63;
    const int wid = tid >> 6;
    const int wr = wid >> 1, wc = wid & 1;
    const int lrow = lane & 15, lk = (lane >> 4) * 8;
    const int row0 = blockIdx.x * 128, col0 = blockIdx.y * 128;
    const short* gA = A + (size_t)row0 * K;
    const short* gB = Bt + (size_t)col0 * K;

    auto stage = [&](int buf, int kt) {
#pragma unroll
        for (int c = 0; c < 4; ++c) {
            int off = c * 4096 + tid * 16;  // byte offset within 16KB tile
            int row = off >> 7, kb = off & 127;
            gload_lds16(gA + (size_t)row * K + kt + (kb >> 1), (char*)&lds[buf][0][0] + off);
            gload_lds16(gB + (size_t)row * K + kt + (kb >> 1), (char*)&lds[buf][1][0] + off);
        }
    };

    ffrag acc[4][4] = {};
    stage(0, 0);
    __syncthreads();
    const int NT = K / 64;
    int cur = 0;
    for (int kt = 0; kt < NT; ++kt) {
        if (kt + 1 < NT) stage(cur ^ 1, (kt + 1) * 64);
        const short* As = &lds[cur][0][0];
        const short* Bs = &lds[cur][1][0];
#pragma unroll
        for (int kk = 0; kk < 2; ++kk) {
            bfrag a[4], b[4];
#pragma unroll
            for (int m = 0; m < 4; ++m)
                a[m] = *(const bfrag*)&As[(wr * 64 + m * 16 + lrow) * 64 + kk * 32 + lk];
#pragma unroll
            for (int n = 0; n < 4; ++n)
                b[n] = *(const bfrag*)&Bs[(wc * 64 + n * 16 + lrow) * 64 + kk * 32 + lk];
#pragma unroll
            for (int m = 0; m < 4; ++m)
#pragma unroll
                for (int n = 0; n < 4; ++n)
                    acc[m][n] = __builtin_amdgcn_mfma_f32_16x16x32_bf16(a[m], b[n], acc[m][n], 0, 0, 0);
        }
        __syncthreads();
        cur ^= 1;
    }

    // epilogue: bias + relu, store
    const int orow = row0 + wr * 64 + (lane >> 4) * 4;
    const int ocol = col0 + wc * 64 + lrow;
#pragma unroll
    for (int n = 0; n < 4; ++n) {
        float bv = bias[ocol + n * 16];
#pragma unroll
        for (int m = 0; m < 4; ++m) {
#pragma unroll
            for (int r = 0; r < 4; ++r) {
                float v = fmaxf(acc[m][n][r] + bv, 0.f);
                size_t idx = (size_t)(orow + m * 16 + r) * N + (ocol + n * 16);
                if constexpr (OUT_BF16)
                    ((short*)Cv)[idx] = f2bf(v);
                else
                    ((float*)Cv)[idx] = v;
            }
        }
    }
}

extern "C" void kernel_launch(void* const* d_in, const int* in_sizes, int n_in,
                              void* d_out, int out_size, void* d_ws, size_t ws_size,
                              hipStream_t stream) {
    const float* nodes = (const float*)d_in[0];
    const int*   edges = (const int*)d_in[1];
    const float* W0    = (const float*)d_in[2];
    const float* b0    = (const float*)d_in[3];
    const float* W1    = (const float*)d_in[4];
    const float* b1    = (const float*)d_in[5];
    float* out = (float*)d_out;

    char* ws = (char*)d_ws;
    size_t off = 0;
    auto alloc = [&](size_t bytes) -> char* {
        char* p = ws + off;
        off = (off + bytes + 255) & ~(size_t)255;
        return p;
    };
    float* dinv   = (float*)alloc((size_t)NB * NN * 4);
    int*   counts = (int*)alloc((size_t)NB * NN * 4);
    int*   offs   = (int*)alloc((size_t)NB * (NN + 1) * 4);
    int*   cursor = (int*)alloc((size_t)NB * NN * 4);
    int*   csr    = (int*)alloc((size_t)NB * NE * 4);
    short* W0t    = (short*)alloc((size_t)HID * OBS * 2);
    short* W1t    = (short*)alloc((size_t)OUTF * HID * 2);
    short* z0     = (short*)alloc((size_t)NB * NN * OBS * 2);   // 4 MB
    short* x1     = (short*)alloc((size_t)NB * NN * HID * 2);   // 8 MB
    short* z1     = (short*)alloc((size_t)NB * NN * HID * 2);   // 8 MB

    hipMemsetAsync(counts, 0, (size_t)NB * NN * 4, stream);
    k_count<<<(NB * NE + 255) / 256, 256, 0, stream>>>(edges, counts);
    k_wt<OBS, HID><<<(OBS * HID + 255) / 256, 256, 0, stream>>>(W0, W0t);
    k_wt<HID, OUTF><<<(HID * OUTF + 255) / 256, 256, 0, stream>>>(W1, W1t);
    k_scan<<<NB, 256, 0, stream>>>(counts, offs, cursor, dinv);
    k_fill<<<(NB * NE + 255) / 256, 256, 0, stream>>>(edges, cursor, csr);

    // Layer 1: z0 = S.nodes ; x1 = relu(z0 @ W0 + b0)   [bf16]
    k_agg0<<<dim3(NN, NB), 64, 0, stream>>>(nodes, dinv, csr, offs, (unsigned*)z0);
    gemm_mfma<OBS, HID, true><<<dim3(NB * NN / 128, HID / 128), 256, 0, stream>>>(z0, W0t, b0, x1);

    // Layer 2: z1 = S.x1 ; out = relu(z1 @ W1 + b1)     [f32 out]
    k_agg1<<<dim3(NN, NB), 64, 0, stream>>>(x1, dinv, csr, offs, (unsigned*)z1);
    gemm_mfma<HID, OUTF, false><<<dim3(NB * NN / 128, OUTF / 128), 256, 0, stream>>>(z1, W1t, b1, out);
}

// Round 3
// 80.439 us; speedup vs baseline: 3.1095x; 1.0555x over previous
//
#include <hip/hip_runtime.h>
#include <hip/hip_bf16.h>
#include <stdint.h>

#define NB   8
#define NN   2048
#define NE   16384
#define OBS  128
#define HID  256
#define OUTF 1024

using bfrag = __attribute__((ext_vector_type(8))) short;
using ffrag = __attribute__((ext_vector_type(4))) float;

__device__ __forceinline__ short f2bf(float f) {
    __hip_bfloat16 h = __float2bfloat16(f);
    return __builtin_bit_cast(short, h);
}
__device__ __forceinline__ unsigned packbf(float a, float b) {
    return ((unsigned)(unsigned short)f2bf(b) << 16) | (unsigned)(unsigned short)f2bf(a);
}

__device__ __forceinline__ void gload_lds16(const void* g, void* l) {
    __builtin_amdgcn_global_load_lds(
        (const __attribute__((address_space(1))) unsigned int*)g,
        (__attribute__((address_space(3))) unsigned int*)l, 16, 0, 0);
}

// ---------------- fused prep: W0^T, W1^T (f32->bf16) + zero counts ----------------
__global__ __launch_bounds__(256) void k_prep(const float* __restrict__ W0,
                                              const float* __restrict__ W1,
                                              short* __restrict__ W0t,
                                              short* __restrict__ W1t,
                                              int* __restrict__ counts) {
    int idx = blockIdx.x * 256 + threadIdx.x;
    if (idx < HID * OUTF) {  // W1t [OUTF][HID]
        int n = idx / HID, k = idx - n * HID;
        W1t[idx] = f2bf(W1[k * OUTF + n]);
    }
    if (idx < OBS * HID) {   // W0t [HID][OBS]
        int n = idx / OBS, k = idx - n * OBS;
        W0t[idx] = f2bf(W0[k * HID + n]);
    }
    if (idx < NB * NN) counts[idx] = 0;
}

// ---------------- graph setup ----------------
__global__ __launch_bounds__(256) void k_count(const int* __restrict__ edges,
                                               int* __restrict__ counts) {
    int idx = blockIdx.x * 256 + threadIdx.x;
    if (idx >= NB * NE) return;
    int b = idx / NE, e = idx - b * NE;
    int dst = edges[(size_t)b * 2 * NE + NE + e];
    atomicAdd(&counts[b * NN + dst], 1);
}

__global__ __launch_bounds__(256) void k_scan(const int* __restrict__ counts,
                                              int* __restrict__ offsets,
                                              int* __restrict__ cursor,
                                              float* __restrict__ dinv) {
    const int b = blockIdx.x, t = threadIdx.x;
    const int base = b * NN + t * 8;
    int local[8];
    int s = 0;
#pragma unroll
    for (int j = 0; j < 8; ++j) {
        int c = counts[base + j];
        local[j] = s;
        s += c;
        dinv[base + j] = rsqrtf((float)(c + 1));
    }
    __shared__ int sc[256];
    sc[t] = s;
    __syncthreads();
    for (int d = 1; d < 256; d <<= 1) {
        int v = (t >= d) ? sc[t - d] : 0;
        __syncthreads();
        if (t >= d) sc[t] += v;
        __syncthreads();
    }
    int excl = sc[t] - s;
#pragma unroll
    for (int j = 0; j < 8; ++j) {
        int val = excl + local[j];
        offsets[b * (NN + 1) + t * 8 + j] = val;
        cursor[base + j] = val;
    }
    if (t == 0) offsets[b * (NN + 1) + NN] = NE;
}

// CSR fill + per-edge precomputed norm = dinv[dst]*dinv[src]
__global__ __launch_bounds__(256) void k_fill(const int* __restrict__ edges,
                                              const float* __restrict__ dinv,
                                              int* __restrict__ cursor,
                                              int* __restrict__ csr,
                                              float* __restrict__ wcsr) {
    int idx = blockIdx.x * 256 + threadIdx.x;
    if (idx >= NB * NE) return;
    int b = idx / NE, e = idx - b * NE;
    int src = edges[(size_t)b * 2 * NE + e];
    int dst = edges[(size_t)b * 2 * NE + NE + e];
    int pos = atomicAdd(&cursor[b * NN + dst], 1);
    csr[(size_t)b * NE + pos] = src;
    wcsr[(size_t)b * NE + pos] = dinv[b * NN + dst] * dinv[b * NN + src];
}

// ---------------- pre-GEMM aggregation (S x) ----------------
// z0 = S . nodes  (f32 in -> bf16 out, F=128). 64 thr x 2 elems.
__global__ __launch_bounds__(64) void k_agg0(const float* __restrict__ nodes,
                                             const float* __restrict__ dinv,
                                             const int* __restrict__ csr,
                                             const float* __restrict__ wcsr,
                                             const int* __restrict__ offs,
                                             unsigned* __restrict__ z0) {
    const int i = blockIdx.x, b = blockIdx.y, t = threadIdx.x;
    const float* xb = nodes + (size_t)b * NN * OBS;
    const float di = dinv[b * NN + i];
    const int o0 = offs[b * (NN + 1) + i], o1 = offs[b * (NN + 1) + i + 1];
    float2 v = *(const float2*)&xb[(size_t)i * OBS + t * 2];
    float ax = di * di * v.x, ay = di * di * v.y;
    const int* cs = csr + (size_t)b * NE;
    const float* wc = wcsr + (size_t)b * NE;
    for (int e = o0; e < o1; ++e) {
        int s = cs[e];
        float w = wc[e];
        float2 u = *(const float2*)&xb[(size_t)s * OBS + t * 2];
        ax = fmaf(w, u.x, ax);
        ay = fmaf(w, u.y, ay);
    }
    z0[(((size_t)b * NN + i) * OBS + t * 2) >> 1] = packbf(ax, ay);
}

// z1 = S . x1  (bf16 in -> bf16 out, F=256). 64 thr x 4 elems.
__global__ __launch_bounds__(64) void k_agg1(const short* __restrict__ x1,
                                             const float* __restrict__ dinv,
                                             const int* __restrict__ csr,
                                             const float* __restrict__ wcsr,
                                             const int* __restrict__ offs,
                                             unsigned* __restrict__ z1) {
    const int i = blockIdx.x, b = blockIdx.y, t = threadIdx.x;
    const short* xb = x1 + (size_t)b * NN * HID;
    const float di = dinv[b * NN + i];
    const int o0 = offs[b * (NN + 1) + i], o1 = offs[b * (NN + 1) + i + 1];
    uint2 raw = *(const uint2*)&xb[(size_t)i * HID + t * 4];
    float di2 = di * di;
    float a0 = di2 * __uint_as_float(raw.x << 16);
    float a1 = di2 * __uint_as_float(raw.x & 0xffff0000u);
    float a2 = di2 * __uint_as_float(raw.y << 16);
    float a3 = di2 * __uint_as_float(raw.y & 0xffff0000u);
    const int* cs = csr + (size_t)b * NE;
    const float* wc = wcsr + (size_t)b * NE;
    for (int e = o0; e < o1; ++e) {
        int s = cs[e];
        float w = wc[e];
        uint2 u = *(const uint2*)&xb[(size_t)s * HID + t * 4];
        a0 = fmaf(w, __uint_as_float(u.x << 16), a0);
        a1 = fmaf(w, __uint_as_float(u.x & 0xffff0000u), a1);
        a2 = fmaf(w, __uint_as_float(u.y << 16), a2);
        a3 = fmaf(w, __uint_as_float(u.y & 0xffff0000u), a3);
    }
    uint2 o;
    o.x = packbf(a0, a1);
    o.y = packbf(a2, a3);
    *(uint2*)&z1[(((size_t)b * NN + i) * HID + t * 4) >> 1] = o;
}

// ---------------- bf16 MFMA GEMM: C = relu(A @ Bt^T + bias) ----------------
// A [M][K] bf16 row-major, Bt [N][K] bf16 (pre-transposed weights).
// 128x128 tile, BK=64, 4 waves (2x2 of 64x64), double-buffered LDS,
// global_load_lds width-16 staging (m97 structure).
template <int K, int N, bool OUT_BF16>
__global__ __launch_bounds__(256, 2) void gemm_mfma(const short* __restrict__ A,
                                                    const short* __restrict__ Bt,
                                                    const float* __restrict__ bias,
                                                    void* __restrict__ Cv) {
    __shared__ short lds[2][2][128 * 64];  // [buf][A|B][row*64 + k] bf16
    const int tid = threadIdx.x;
    const int lane = tid & 63;
    const int wid = tid >> 6;
    const int wr = wid >> 1, wc = wid & 1;
    const int lrow = lane & 15, lk = (lane >> 4) * 8;
    const int row0 = blockIdx.x * 128, col0 = blockIdx.y * 128;
    const short* gA = A + (size_t)row0 * K;
    const short* gB = Bt + (size_t)col0 * K;

    auto stage = [&](int buf, int kt) {
#pragma unroll
        for (int c = 0; c < 4; ++c) {
            int off = c * 4096 + tid * 16;  // byte offset within 16KB tile
            int row = off >> 7, kb = off & 127;
            gload_lds16(gA + (size_t)row * K + kt + (kb >> 1), (char*)&lds[buf][0][0] + off);
            gload_lds16(gB + (size_t)row * K + kt + (kb >> 1), (char*)&lds[buf][1][0] + off);
        }
    };

    ffrag acc[4][4] = {};
    stage(0, 0);
    __syncthreads();
    const int NT = K / 64;
    int cur = 0;
    for (int kt = 0; kt < NT; ++kt) {
        if (kt + 1 < NT) stage(cur ^ 1, (kt + 1) * 64);
        const short* As = &lds[cur][0][0];
        const short* Bs = &lds[cur][1][0];
#pragma unroll
        for (int kk = 0; kk < 2; ++kk) {
            bfrag a[4], b[4];
#pragma unroll
            for (int m = 0; m < 4; ++m)
                a[m] = *(const bfrag*)&As[(wr * 64 + m * 16 + lrow) * 64 + kk * 32 + lk];
#pragma unroll
            for (int n = 0; n < 4; ++n)
                b[n] = *(const bfrag*)&Bs[(wc * 64 + n * 16 + lrow) * 64 + kk * 32 + lk];
#pragma unroll
            for (int m = 0; m < 4; ++m)
#pragma unroll
                for (int n = 0; n < 4; ++n)
                    acc[m][n] = __builtin_amdgcn_mfma_f32_16x16x32_bf16(a[m], b[n], acc[m][n], 0, 0, 0);
        }
        __syncthreads();
        cur ^= 1;
    }

    // epilogue: bias + relu, store
    const int orow = row0 + wr * 64 + (lane >> 4) * 4;
    const int ocol = col0 + wc * 64 + lrow;
#pragma unroll
    for (int n = 0; n < 4; ++n) {
        float bv = bias[ocol + n * 16];
#pragma unroll
        for (int m = 0; m < 4; ++m) {
#pragma unroll
            for (int r = 0; r < 4; ++r) {
                float v = fmaxf(acc[m][n][r] + bv, 0.f);
                size_t idx = (size_t)(orow + m * 16 + r) * N + (ocol + n * 16);
                if constexpr (OUT_BF16)
                    ((short*)Cv)[idx] = f2bf(v);
                else
                    ((float*)Cv)[idx] = v;
            }
        }
    }
}

extern "C" void kernel_launch(void* const* d_in, const int* in_sizes, int n_in,
                              void* d_out, int out_size, void* d_ws, size_t ws_size,
                              hipStream_t stream) {
    const float* nodes = (const float*)d_in[0];
    const int*   edges = (const int*)d_in[1];
    const float* W0    = (const float*)d_in[2];
    const float* b0    = (const float*)d_in[3];
    const float* W1    = (const float*)d_in[4];
    const float* b1    = (const float*)d_in[5];
    float* out = (float*)d_out;

    char* ws = (char*)d_ws;
    size_t off = 0;
    auto alloc = [&](size_t bytes) -> char* {
        char* p = ws + off;
        off = (off + bytes + 255) & ~(size_t)255;
        return p;
    };
    float* dinv   = (float*)alloc((size_t)NB * NN * 4);
    int*   counts = (int*)alloc((size_t)NB * NN * 4);
    int*   offs   = (int*)alloc((size_t)NB * (NN + 1) * 4);
    int*   cursor = (int*)alloc((size_t)NB * NN * 4);
    int*   csr    = (int*)alloc((size_t)NB * NE * 4);
    float* wcsr   = (float*)alloc((size_t)NB * NE * 4);
    short* W0t    = (short*)alloc((size_t)HID * OBS * 2);
    short* W1t    = (short*)alloc((size_t)OUTF * HID * 2);
    short* z0     = (short*)alloc((size_t)NB * NN * OBS * 2);   // 4 MB
    short* x1     = (short*)alloc((size_t)NB * NN * HID * 2);   // 8 MB
    short* z1     = (short*)alloc((size_t)NB * NN * HID * 2);   // 8 MB

    // 1: weight transposes + zero counts (replaces memset + 2 k_wt launches)
    k_prep<<<(HID * OUTF + 255) / 256, 256, 0, stream>>>(W0, W1, W0t, W1t, counts);
    // 2-4: degree count -> scan (offsets, dinv) -> CSR fill (+ per-edge norm)
    k_count<<<(NB * NE + 255) / 256, 256, 0, stream>>>(edges, counts);
    k_scan<<<NB, 256, 0, stream>>>(counts, offs, cursor, dinv);
    k_fill<<<(NB * NE + 255) / 256, 256, 0, stream>>>(edges, dinv, cursor, csr, wcsr);

    // 5-6: Layer 1: z0 = S.nodes ; x1 = relu(z0 @ W0 + b0)   [bf16]
    k_agg0<<<dim3(NN, NB), 64, 0, stream>>>(nodes, dinv, csr, wcsr, offs, (unsigned*)z0);
    gemm_mfma<OBS, HID, true><<<dim3(NB * NN / 128, HID / 128), 256, 0, stream>>>(z0, W0t, b0, x1);

    // 7-8: Layer 2: z1 = S.x1 ; out = relu(z1 @ W1 + b1)     [f32 out]
    k_agg1<<<dim3(NN, NB), 64, 0, stream>>>(x1, dinv, csr, wcsr, offs, (unsigned*)z1);
    gemm_mfma<HID, OUTF, false><<<dim3(NB * NN / 128, OUTF / 128), 256, 0, stream>>>(z1, W1t, b1, out);
}